// Round 6
// baseline (1064.030 us; speedup 1.0000x reference)
//
#include <hip/hip_runtime.h>
#include <math.h>

// Problem constants
#define BATCH 16
#define CH    64
#define HDIM  256
#define WDIM  256
#define HW    65536        // 256*256
#define KS    7
#define HIDN  16
#define COUT  3136         // CH * KS * KS
#define NPLANE 1024        // BATCH * CH

// float4 with relaxed (4B) alignment for the shifted staging loads
typedef float4 f4u __attribute__((aligned(4)));

// ---------------------------------------------------------------------------
// Kernel 1: global average pool (unchanged from baseline)
// ---------------------------------------------------------------------------
__global__ __launch_bounds__(512) void gap_kernel(const float* __restrict__ x,
                                                  float* __restrict__ pooled) {
    const int p = blockIdx.x;
    const float4* xv = (const float4*)(x + (size_t)p * HW);
    const int t = threadIdx.x;
    float s = 0.f;
    #pragma unroll 4
    for (int i = t; i < 16384; i += 512) {
        float4 a = xv[i];
        s += (a.x + a.y) + (a.z + a.w);
    }
    #pragma unroll
    for (int off = 32; off > 0; off >>= 1) s += __shfl_down(s, off);
    __shared__ float sp[8];
    const int wid = t >> 6, lane = t & 63;
    if (lane == 0) sp[wid] = s;
    __syncthreads();
    if (t == 0) {
        float tot = 0.f;
        #pragma unroll
        for (int i = 0; i < 8; ++i) tot += sp[i];
        pooled[p] = tot * (1.0f / 65536.0f);
    }
}

// ---------------------------------------------------------------------------
// Kernel 2: MLP weight generator (unchanged from baseline)
// ---------------------------------------------------------------------------
__global__ __launch_bounds__(256) void mlp_kernel(const float* __restrict__ pooled,
                                                  const float* __restrict__ w1,
                                                  const float* __restrict__ b1,
                                                  const float* __restrict__ w2,
                                                  const float* __restrict__ b2,
                                                  float* __restrict__ wout) {
    __shared__ float s_pool[NPLANE];
    __shared__ float s_hdn[BATCH * HIDN];
    const int t = threadIdx.x;
    for (int i = t; i < NPLANE; i += 256) s_pool[i] = pooled[i];
    __syncthreads();
    {
        const int i = t >> 4, j = t & 15;
        float acc = b1[j];
        #pragma unroll
        for (int c = 0; c < 64; ++c) acc += s_pool[i * 64 + c] * w1[c * HIDN + j];
        s_hdn[t] = 0.5f * acc * (1.0f + erff(acc * 0.70710678118654752f));
    }
    __syncthreads();
    const int o = blockIdx.x * 256 + t;
    const int i = o / COUT;
    const int j = o - i * COUT;
    float acc = b2[j];
    #pragma unroll
    for (int h = 0; h < HIDN; ++h) acc += s_hdn[i * HIDN + h] * w2[h * COUT + j];
    wout[o] = 1.0f / (1.0f + expf(-acc));
}

// ---------------------------------------------------------------------------
// Kernel 3: depthwise 7x7 conv, reflect pad, dynamic per-plane weights.
//
// Memory config = R0/R5 (cleanest measured traffic: FETCH 180MB, WRITE 1.0x):
// 128x64 tile, grid (2,4,1024) default mapping, plain float4 stores,
// reg->ds_write staging (wave-coalesced full-line transactions).
//
// vs R5 (167us, VALU 40%, HBM 34%, occ 30% => latency-bound, no pipe busy):
//  1. __launch_bounds__(256,4): LDS 38.4KB x 4 = 153.6KB <= 160KB -> 4
//     resident blocks/CU (was 3). +33% cross-block stage/compute overlap.
//  2. Staging split into LOAD-ALL (9 float4 + 6-scalar tail into registers)
//     then WRITE-ALL (ds_write). The fused load->write loop forced a vmcnt
//     wait before each ds_write -> ~1-2 loads in flight; the split keeps all
//     36 load-dwords outstanding (T14 issue-early/write-late), hiding the
//     ~700cy HBM/L2 latency once instead of 9 times.
// ---------------------------------------------------------------------------
#define TLX 128
#define TLY 64
#define INX 134            // TLX + 6
#define INY 70             // TLY + 6
#define LDSS 136           // padded LDS row stride (floats), 544B, 16B-aligned

__global__ __launch_bounds__(256, 4) void conv_kernel(const float* __restrict__ x,
                                                      const float* __restrict__ wts,
                                                      float* __restrict__ out) {
    __shared__ float s_in[INY * LDSS];
    __shared__ float s_w[49];
    const int p = blockIdx.z;
    const size_t pbase = (size_t)p * HW;
    const int gx0 = blockIdx.x * TLX;      // LDS col c holds gx = gx0 - 3 + c
    const int gy0 = blockIdx.y * TLY - 3;
    const int t = threadIdx.x;

    if (t < 49) s_w[t] = wts[p * 49 + t];

    // --- phase 1: issue ALL staging loads into registers -------------------
    // main: 70 rows x 32 float4 (LDS words 0..127 per row); thread t, chunk k
    // covers linear slot i = t + 256k -> row i>>5, col-group (i&31)*4.
    // k = 0..7 always valid (i <= 2047 < 2240); k = 8 valid for t < 192.
    float4 v[9];
    #pragma unroll
    for (int k = 0; k < 9; ++k) {
        const int i = t + 256 * k;
        const int r = i >> 5;
        if (k < 8 || t < 192) {
            const int c4 = (i & 31) << 2;
            int gy = gy0 + r;
            gy = gy < 0 ? -gy : (gy > 255 ? 510 - gy : gy);
            const float* rowp = x + pbase + ((size_t)gy << 8);
            const int gxs = gx0 - 3 + c4;
            if (gxs >= 0) {
                v[k] = *(const f4u*)(rowp + gxs);
            } else {                        // only bx==0, c4==0: gx=-3..0
                float4 u = *(const float4*)(rowp);    // x[0..3]
                v[k] = make_float4(u.w, u.z, u.y, u.x);
            }
        }
    }
    // tail: cols 128..133 (gx = gx0+125..130; right reflect for bx==1)
    float tv[6];
    if (t < INY) {
        int gy = gy0 + t;
        gy = gy < 0 ? -gy : (gy > 255 ? 510 - gy : gy);
        const float* rowp = x + pbase + ((size_t)gy << 8);
        #pragma unroll
        for (int j = 0; j < 6; ++j) {
            int gx = gx0 - 3 + 128 + j;
            gx = gx > 255 ? 510 - gx : gx;
            tv[j] = rowp[gx];
        }
    }

    // --- phase 2: write everything to LDS ----------------------------------
    #pragma unroll
    for (int k = 0; k < 9; ++k) {
        const int i = t + 256 * k;
        if (k < 8 || t < 192) {
            const int r = i >> 5;
            const int c4 = (i & 31) << 2;
            *(float4*)&s_in[r * LDSS + c4] = v[k];
        }
    }
    if (t < INY) {
        #pragma unroll
        for (int j = 0; j < 6; ++j) s_in[t * LDSS + 128 + j] = tv[j];
    }
    __syncthreads();

    float w[49];
    #pragma unroll
    for (int i = 0; i < 49; ++i) w[i] = s_w[i];

    const int tx4 = (t & 31) * 4;        // output col within tile (0..124)
    const int ty  = (t >> 5) * 8;        // output row within tile (0..56)

    float acc[32];
    #pragma unroll
    for (int i = 0; i < 32; ++i) acc[i] = 0.f;

    // vertical sliding window over 14 input rows -> 8 output rows
    #pragma unroll
    for (int r = 0; r < 14; ++r) {
        const float* rp = &s_in[(ty + r) * LDSS + tx4];
        const float4 v0 = *(const float4*)(rp);
        const float4 v1 = *(const float4*)(rp + 4);
        const float4 v2 = *(const float4*)(rp + 8);
        const float row[12] = {v0.x, v0.y, v0.z, v0.w,
                               v1.x, v1.y, v1.z, v1.w,
                               v2.x, v2.y, v2.z, v2.w};
        #pragma unroll
        for (int o = 0; o < 8; ++o) {
            const int ky = r - o;
            if (ky < 0 || ky > 6) continue;      // compile-time resolved
            #pragma unroll
            for (int kx = 0; kx < 7; ++kx) {
                const float wv = w[ky * 7 + kx];
                acc[o * 4 + 0] += wv * row[kx + 0];
                acc[o * 4 + 1] += wv * row[kx + 1];
                acc[o * 4 + 2] += wv * row[kx + 2];
                acc[o * 4 + 3] += wv * row[kx + 3];
            }
        }
    }

    const int oy0 = blockIdx.y * TLY + ty;
    const int ox  = blockIdx.x * TLX + tx4;
    #pragma unroll
    for (int o = 0; o < 8; ++o) {
        const float4 vv = make_float4(acc[o * 4 + 0], acc[o * 4 + 1],
                                      acc[o * 4 + 2], acc[o * 4 + 3]);
        *(float4*)&out[pbase + (size_t)(oy0 + o) * WDIM + ox] = vv;
    }
}

// ---------------------------------------------------------------------------
extern "C" void kernel_launch(void* const* d_in, const int* in_sizes, int n_in,
                              void* d_out, int out_size, void* d_ws, size_t ws_size,
                              hipStream_t stream) {
    const float* x  = (const float*)d_in[0];
    const float* w1 = (const float*)d_in[1];
    const float* b1 = (const float*)d_in[2];
    const float* w2 = (const float*)d_in[3];
    const float* b2 = (const float*)d_in[4];
    float* out = (float*)d_out;

    float* pooled = (float*)d_ws;           // 1024 floats
    float* wts    = pooled + NPLANE;        // 50176 floats

    gap_kernel<<<NPLANE, 512, 0, stream>>>(x, pooled);
    mlp_kernel<<<(BATCH * COUT) / 256, 256, 0, stream>>>(pooled, w1, b1, w2, b2, wts);
    conv_kernel<<<dim3(WDIM / TLX, HDIM / TLY, NPLANE), 256, 0, stream>>>(x, wts, out);
}

// Round 7
// 556.876 us; speedup vs baseline: 1.9107x; 1.9107x over previous
//
#include <hip/hip_runtime.h>
#include <math.h>

// Problem constants
#define BATCH 16
#define CH    64
#define HDIM  256
#define WDIM  256
#define HW    65536        // 256*256
#define KS    7
#define HIDN  16
#define COUT  3136         // CH * KS * KS
#define NPLANE 1024        // BATCH * CH

// float4 with relaxed (4B) alignment for the shifted staging loads
typedef float4 f4u __attribute__((aligned(4)));

// ---------------------------------------------------------------------------
// Kernel 1: global average pool (unchanged from baseline)
// ---------------------------------------------------------------------------
__global__ __launch_bounds__(512) void gap_kernel(const float* __restrict__ x,
                                                  float* __restrict__ pooled) {
    const int p = blockIdx.x;
    const float4* xv = (const float4*)(x + (size_t)p * HW);
    const int t = threadIdx.x;
    float s = 0.f;
    #pragma unroll 4
    for (int i = t; i < 16384; i += 512) {
        float4 a = xv[i];
        s += (a.x + a.y) + (a.z + a.w);
    }
    #pragma unroll
    for (int off = 32; off > 0; off >>= 1) s += __shfl_down(s, off);
    __shared__ float sp[8];
    const int wid = t >> 6, lane = t & 63;
    if (lane == 0) sp[wid] = s;
    __syncthreads();
    if (t == 0) {
        float tot = 0.f;
        #pragma unroll
        for (int i = 0; i < 8; ++i) tot += sp[i];
        pooled[p] = tot * (1.0f / 65536.0f);
    }
}

// ---------------------------------------------------------------------------
// Kernel 2: MLP weight generator (unchanged from baseline)
// ---------------------------------------------------------------------------
__global__ __launch_bounds__(256) void mlp_kernel(const float* __restrict__ pooled,
                                                  const float* __restrict__ w1,
                                                  const float* __restrict__ b1,
                                                  const float* __restrict__ w2,
                                                  const float* __restrict__ b2,
                                                  float* __restrict__ wout) {
    __shared__ float s_pool[NPLANE];
    __shared__ float s_hdn[BATCH * HIDN];
    const int t = threadIdx.x;
    for (int i = t; i < NPLANE; i += 256) s_pool[i] = pooled[i];
    __syncthreads();
    {
        const int i = t >> 4, j = t & 15;
        float acc = b1[j];
        #pragma unroll
        for (int c = 0; c < 64; ++c) acc += s_pool[i * 64 + c] * w1[c * HIDN + j];
        s_hdn[t] = 0.5f * acc * (1.0f + erff(acc * 0.70710678118654752f));
    }
    __syncthreads();
    const int o = blockIdx.x * 256 + t;
    const int i = o / COUT;
    const int j = o - i * COUT;
    float acc = b2[j];
    #pragma unroll
    for (int h = 0; h < HIDN; ++h) acc += s_hdn[i * HIDN + h] * w2[h * COUT + j];
    wout[o] = 1.0f / (1.0f + expf(-acc));
}

// ---------------------------------------------------------------------------
// Kernel 3: depthwise 7x7 conv, reflect pad, dynamic per-plane weights.
//
// = R5 exactly (167us conv, FETCH 180MB, WRITE 1.0x, VGPR 84 - the known-
// clean build; R6's launch_bounds(256,4) capped VGPR at 64 and spilled:
// FETCH/WRITE exploded to 1.05/1.59GB with write>fetch = scratch signature).
//
// SINGLE change vs R5: conv consumes planes in REVERSE order
// (p = 1023 - blockIdx.z). gap_kernel reads x (268MB ~= 1.05x L3) in
// ascending plane order right before conv; same-order consumption is the
// LRU worst case (plane 0 evicted longest ago, read first -> ~0% reuse,
// measured FETCH ~= full re-read). Reversed, conv starts on the planes gap
// touched last (still L3-resident) and sweeps behind gap's LRU tail ->
// loads shift HBM(~900cy) -> L3/L2(~200-350cy), cutting both the exposed
// latency per block and FETCH_SIZE.
// ---------------------------------------------------------------------------
#define TLX 128
#define TLY 64
#define INX 134            // TLX + 6
#define INY 70             // TLY + 6
#define LDSS 136           // padded LDS row stride (floats), 544B, 16B-aligned

__global__ __launch_bounds__(256, 3) void conv_kernel(const float* __restrict__ x,
                                                      const float* __restrict__ wts,
                                                      float* __restrict__ out) {
    __shared__ float s_in[INY * LDSS];
    __shared__ float s_w[49];
    const int p = (NPLANE - 1) - blockIdx.z;   // reverse plane sweep (L3 reuse)
    const size_t pbase = (size_t)p * HW;
    const int gx0 = blockIdx.x * TLX;      // LDS col c holds gx = gx0 - 3 + c
    const int gy0 = blockIdx.y * TLY - 3;
    const int t = threadIdx.x;

    if (t < 49) s_w[t] = wts[p * 49 + t];

    // --- main staging: 70 rows x 32 float4 (LDS words 0..127 per row) ---
    #pragma unroll
    for (int k = 0; k < 9; ++k) {
        const int i = t + 256 * k;
        const int r = i >> 5;              // row (shift, no div)
        if (r < INY) {
            const int c4 = (i & 31) << 2;  // col group 0,4,...,124
            int gy = gy0 + r;
            gy = gy < 0 ? -gy : (gy > 255 ? 510 - gy : gy);
            const float* rowp = x + pbase + ((size_t)gy << 8);
            const int gxs = gx0 - 3 + c4;  // gx of first element
            float4 v;
            if (gxs >= 0) {
                v = *(const f4u*)(rowp + gxs);
            } else {                       // only bx==0, c4==0: gx=-3..0
                float4 u = *(const float4*)(rowp);   // x[0..3]
                v = make_float4(u.w, u.z, u.y, u.x); // reflect = reversed
            }
            *(float4*)&s_in[r * LDSS + c4] = v;
        }
    }
    // --- tail: cols 128..133 (gx = gx0+125..130; right reflect for bx==1) ---
    if (t < INY) {
        int gy = gy0 + t;
        gy = gy < 0 ? -gy : (gy > 255 ? 510 - gy : gy);
        const float* rowp = x + pbase + ((size_t)gy << 8);
        #pragma unroll
        for (int j = 0; j < 6; ++j) {
            int gx = gx0 - 3 + 128 + j;
            gx = gx > 255 ? 510 - gx : gx;
            s_in[t * LDSS + 128 + j] = rowp[gx];
        }
    }
    __syncthreads();

    float w[49];
    #pragma unroll
    for (int i = 0; i < 49; ++i) w[i] = s_w[i];

    const int tx4 = (t & 31) * 4;        // output col within tile (0..124)
    const int ty  = (t >> 5) * 8;        // output row within tile (0..56)

    float acc[32];
    #pragma unroll
    for (int i = 0; i < 32; ++i) acc[i] = 0.f;

    // vertical sliding window over 14 input rows -> 8 output rows
    #pragma unroll
    for (int r = 0; r < 14; ++r) {
        const float* rp = &s_in[(ty + r) * LDSS + tx4];
        const float4 v0 = *(const float4*)(rp);
        const float4 v1 = *(const float4*)(rp + 4);
        const float4 v2 = *(const float4*)(rp + 8);
        const float row[12] = {v0.x, v0.y, v0.z, v0.w,
                               v1.x, v1.y, v1.z, v1.w,
                               v2.x, v2.y, v2.z, v2.w};
        #pragma unroll
        for (int o = 0; o < 8; ++o) {
            const int ky = r - o;
            if (ky < 0 || ky > 6) continue;      // compile-time resolved
            #pragma unroll
            for (int kx = 0; kx < 7; ++kx) {
                const float wv = w[ky * 7 + kx];
                acc[o * 4 + 0] += wv * row[kx + 0];
                acc[o * 4 + 1] += wv * row[kx + 1];
                acc[o * 4 + 2] += wv * row[kx + 2];
                acc[o * 4 + 3] += wv * row[kx + 3];
            }
        }
    }

    const int oy0 = blockIdx.y * TLY + ty;
    const int ox  = blockIdx.x * TLX + tx4;
    #pragma unroll
    for (int o = 0; o < 8; ++o) {
        const float4 v = make_float4(acc[o * 4 + 0], acc[o * 4 + 1],
                                     acc[o * 4 + 2], acc[o * 4 + 3]);
        *(float4*)&out[pbase + (size_t)(oy0 + o) * WDIM + ox] = v;
    }
}

// ---------------------------------------------------------------------------
extern "C" void kernel_launch(void* const* d_in, const int* in_sizes, int n_in,
                              void* d_out, int out_size, void* d_ws, size_t ws_size,
                              hipStream_t stream) {
    const float* x  = (const float*)d_in[0];
    const float* w1 = (const float*)d_in[1];
    const float* b1 = (const float*)d_in[2];
    const float* w2 = (const float*)d_in[3];
    const float* b2 = (const float*)d_in[4];
    float* out = (float*)d_out;

    float* pooled = (float*)d_ws;           // 1024 floats
    float* wts    = pooled + NPLANE;        // 50176 floats

    gap_kernel<<<NPLANE, 512, 0, stream>>>(x, pooled);
    mlp_kernel<<<(BATCH * COUT) / 256, 256, 0, stream>>>(pooled, w1, b1, w2, b2, wts);
    conv_kernel<<<dim3(WDIM / TLX, HDIM / TLY, NPLANE), 256, 0, stream>>>(x, wts, out);
}